// Round 7
// baseline (23.344 us; speedup 1.0000x reference)
//
#include <hip/hip_runtime.h>
#include <hip/hip_bf16.h>

#define IN_FEATS 128
#define HIDDEN 32

typedef __attribute__((ext_vector_type(8))) short bf16x8;   // 8 bf16 (4 VGPRs)
typedef __attribute__((ext_vector_type(4))) float f32x4;
typedef _Float16 f16;
typedef __attribute__((ext_vector_type(2))) _Float16 f16x2;
typedef __attribute__((ext_vector_type(8))) _Float16 f16x8; // 16 B

// fp32 -> bf16 round-to-nearest-even (bit trick; NaN irrelevant for this data)
static __device__ __forceinline__ short f2bf(float f) {
    union { float f; unsigned u; } v;
    v.f = f;
    unsigned r = v.u + 0x7FFFu + ((v.u >> 16) & 1u);
    return (short)(r >> 16);
}

// Kernel 1 (MFMA, LDS-staged): p[n] = fp16( h[n] @ W1 + 0.5*b1 )
// Block = 256 thr = 4 waves, 64 rows/block, 625 blocks.
// h staged to LDS with coalesced float4 loads (fixes the row-strided A-frag
// gather that made each wave cost ~512 L1 txns); W1 frag loads issued before
// the barrier to overlap staging latency.
__global__ __launch_bounds__(256) void node_proj_mfma(
    const float* __restrict__ h,
    const float* __restrict__ W1,
    const float* __restrict__ b1,
    f16* __restrict__ p,               // fp16 out
    int n_nodes) {
    __shared__ float hs[64][130];      // pad 2 floats: 4-way-max bank conflicts

    const int t = threadIdx.x;
    const int row0 = blockIdx.x * 64;

    // ---- Stage 64 rows of h (32 KB) with coalesced float4 reads ----
    {
        const float4* hg = (const float4*)(h + (size_t)row0 * IN_FEATS);
        const bool full = (row0 + 64 <= n_nodes);
#pragma unroll
        for (int i = 0; i < 8; ++i) {
            const int idx = t + i * 256;       // 0..2047
            const int r = idx >> 5;            // row within tile
            const int c4 = idx & 31;           // float4 within row
            float4 v = make_float4(0.f, 0.f, 0.f, 0.f);
            if (full || row0 + r < n_nodes) v = hg[idx];
            // 8B-aligned LDS writes (row stride 520 B)
            *(float2*)&hs[r][c4 * 4]     = make_float2(v.x, v.y);
            *(float2*)&hs[r][c4 * 4 + 2] = make_float2(v.z, v.w);
        }
    }

    const int lane = t & 63;
    const int wave = t >> 6;
    const int lr = lane & 15;
    const int kg = lane >> 4;

    // ---- W1 B-frags from global (16 KB, L1-resident); overlaps staging ----
    bf16x8 bfrag[2][4];
#pragma unroll
    for (int ct = 0; ct < 2; ++ct) {
#pragma unroll
        for (int ks = 0; ks < 4; ++ks) {
            const float* wp = W1 + (size_t)(ks * 32 + kg * 8) * HIDDEN + ct * 16 + lr;
#pragma unroll
            for (int i = 0; i < 8; ++i)
                bfrag[ct][ks][i] = f2bf(wp[(size_t)i * HIDDEN]);
        }
    }

    const float hb0 = 0.5f * b1[lr];
    const float hb1 = 0.5f * b1[16 + lr];

    __syncthreads();

    // ---- A-frags from LDS (float2 reads, 4-way conflicts max) ----
    const int arow = wave * 16 + lr;
    bf16x8 afrag[4];
#pragma unroll
    for (int ks = 0; ks < 4; ++ks) {
        const float* s = &hs[arow][kg * 8 + ks * 32];
        const float2 f0 = *(const float2*)(s);
        const float2 f1 = *(const float2*)(s + 2);
        const float2 f2 = *(const float2*)(s + 4);
        const float2 f3 = *(const float2*)(s + 6);
        afrag[ks][0] = f2bf(f0.x);
        afrag[ks][1] = f2bf(f0.y);
        afrag[ks][2] = f2bf(f1.x);
        afrag[ks][3] = f2bf(f1.y);
        afrag[ks][4] = f2bf(f2.x);
        afrag[ks][5] = f2bf(f2.y);
        afrag[ks][6] = f2bf(f3.x);
        afrag[ks][7] = f2bf(f3.y);
    }

    f32x4 acc0 = {hb0, hb0, hb0, hb0};
    f32x4 acc1 = {hb1, hb1, hb1, hb1};
#pragma unroll
    for (int ks = 0; ks < 4; ++ks) {
        acc0 = __builtin_amdgcn_mfma_f32_16x16x32_bf16(afrag[ks], bfrag[0][ks], acc0, 0, 0, 0);
        acc1 = __builtin_amdgcn_mfma_f32_16x16x32_bf16(afrag[ks], bfrag[1][ks], acc1, 0, 0, 0);
    }

    // ---- Store fp16: D[row=(kg*4+r)][col=ct*16+lr] ----
    const int orow0 = row0 + wave * 16;
    if (orow0 + 16 <= n_nodes) {
        f16* prow = p + (size_t)orow0 * HIDDEN;
#pragma unroll
        for (int r = 0; r < 4; ++r) {
            prow[(size_t)(kg * 4 + r) * HIDDEN + lr]      = (f16)acc0[r];
            prow[(size_t)(kg * 4 + r) * HIDDEN + 16 + lr] = (f16)acc1[r];
        }
    } else {
#pragma unroll
        for (int r = 0; r < 4; ++r) {
            const int rr = orow0 + kg * 4 + r;
            if (rr < n_nodes) {
                p[(size_t)rr * HIDDEN + lr]      = (f16)acc0[r];
                p[(size_t)rr * HIDDEN + 16 + lr] = (f16)acc1[r];
            }
        }
    }
}

// Kernel 2: 4 lanes per edge, 4 consecutive edges per slot, packed fp16 math.
// Per edge: 2 x 16B row-gathers per lane-group (1 cache line per row), then
// v_pk_add_f16 + v_pk_max_f16 + v_dot2_f32_f16, 2-step shfl reduce.
__global__ __launch_bounds__(256) void edge_mlp_f16(
    const f16* __restrict__ p,     // fp16 [n_nodes][32], includes +b1/2
    const int* __restrict__ src,
    const int* __restrict__ dst,
    const float* __restrict__ W2,
    const float* __restrict__ b2,
    float* __restrict__ out,
    int n_edges) {
    const int t = threadIdx.x;
    const int q = t & 3;          // 8-unit slot within the 32-unit row
    const int slot = t >> 2;      // edge-group within block (0..63)

    const float4 w0 = ((const float4*)W2)[q * 2];
    const float4 w1 = ((const float4*)W2)[q * 2 + 1];
    f16x2 w2h[4];
    w2h[0] = f16x2{(f16)w0.x, (f16)w0.y};
    w2h[1] = f16x2{(f16)w0.z, (f16)w0.w};
    w2h[2] = f16x2{(f16)w1.x, (f16)w1.y};
    w2h[3] = f16x2{(f16)w1.z, (f16)w1.w};
    const float b2s = b2[0];
    const f16x2 zero2 = f16x2{(f16)0.0f, (f16)0.0f};

    const int e0 = (blockIdx.x * 64 + slot) * 4;
    if (e0 >= n_edges) return;

    if (e0 + 3 < n_edges) {
        const int4 s4 = *(const int4*)(src + e0);   // broadcast within group
        const int4 d4 = *(const int4*)(dst + e0);

        const f16x8 a0 = *(const f16x8*)(p + (size_t)s4.x * HIDDEN + q * 8);
        const f16x8 a1 = *(const f16x8*)(p + (size_t)s4.y * HIDDEN + q * 8);
        const f16x8 a2 = *(const f16x8*)(p + (size_t)s4.z * HIDDEN + q * 8);
        const f16x8 a3 = *(const f16x8*)(p + (size_t)s4.w * HIDDEN + q * 8);
        const f16x8 c0 = *(const f16x8*)(p + (size_t)d4.x * HIDDEN + q * 8);
        const f16x8 c1 = *(const f16x8*)(p + (size_t)d4.y * HIDDEN + q * 8);
        const f16x8 c2 = *(const f16x8*)(p + (size_t)d4.z * HIDDEN + q * 8);
        const f16x8 c3 = *(const f16x8*)(p + (size_t)d4.w * HIDDEN + q * 8);

        const f16x8 A[4] = {a0, a1, a2, a3};
        const f16x8 C[4] = {c0, c1, c2, c3};

        float res[4];
#pragma unroll
        for (int i = 0; i < 4; ++i) {
            float part = 0.0f;
#pragma unroll
            for (int j = 0; j < 4; ++j) {
                f16x2 av = f16x2{A[i][2 * j], A[i][2 * j + 1]};
                f16x2 cv = f16x2{C[i][2 * j], C[i][2 * j + 1]};
                f16x2 sum = av + cv;                              // v_pk_add_f16
                f16x2 rl = __builtin_elementwise_max(sum, zero2); // v_pk_max_f16
#if __has_builtin(__builtin_amdgcn_fdot2)
                part = __builtin_amdgcn_fdot2(rl, w2h[j], part, false);
#else
                part = fmaf((float)rl[0], (float)w2h[j][0], part);
                part = fmaf((float)rl[1], (float)w2h[j][1], part);
#endif
            }
            part += __shfl_xor(part, 1, 4);
            part += __shfl_xor(part, 2, 4);
            res[i] = part + b2s;
        }

        if (q == 0) {
            *(float4*)(out + e0) = make_float4(res[0], res[1], res[2], res[3]);
        }
    } else {
        for (int i = 0; i < 4 && e0 + i < n_edges; ++i) {
            const int s = src[e0 + i];
            const int d = dst[e0 + i];
            const f16x8 a = *(const f16x8*)(p + (size_t)s * HIDDEN + q * 8);
            const f16x8 c = *(const f16x8*)(p + (size_t)d * HIDDEN + q * 8);
            float part = 0.0f;
#pragma unroll
            for (int j = 0; j < 4; ++j) {
                float s0 = (float)a[2 * j] + (float)c[2 * j];
                float s1 = (float)a[2 * j + 1] + (float)c[2 * j + 1];
                part = fmaf(fmaxf(s0, 0.0f), (float)w2h[j][0], part);
                part = fmaf(fmaxf(s1, 0.0f), (float)w2h[j][1], part);
            }
            part += __shfl_xor(part, 1, 4);
            part += __shfl_xor(part, 2, 4);
            if (q == 0) out[e0 + i] = part + b2s;
        }
    }
}

// Fallback (only if ws too small for p): fused, correct, slower.
__global__ __launch_bounds__(256) void fused_edge_kernel(
    const float* __restrict__ h,
    const int* __restrict__ src,
    const int* __restrict__ dst,
    const float* __restrict__ W1,
    const float* __restrict__ b1,
    const float* __restrict__ W2,
    const float* __restrict__ b2,
    float* __restrict__ out,
    int n_edges) {
    __shared__ float W1s[IN_FEATS * HIDDEN];
    __shared__ float sc[8][IN_FEATS];

    const int t = threadIdx.x;
    {
        const float4* W1v = (const float4*)W1;
        float4* W1sv = (float4*)W1s;
#pragma unroll
        for (int i = 0; i < 4; ++i) W1sv[t + i * 256] = W1v[t + i * 256];
    }

    const int le = t >> 5;
    const int j  = t & 31;
    const int e = blockIdx.x * 8 + le;
    __syncthreads();

    if (e < n_edges) {
        const int s = src[e];
        const int d = dst[e];
        const float4* hs4 = (const float4*)(h + (size_t)s * IN_FEATS);
        const float4* hd4 = (const float4*)(h + (size_t)d * IN_FEATS);
        float4* sc4 = (float4*)sc[le];
        float4 a = hs4[j], b = hd4[j];
        sc4[j] = make_float4(a.x + b.x, a.y + b.y, a.z + b.z, a.w + b.w);
    }
    __syncthreads();

    if (e >= n_edges) return;

    float acc = b1[j];
    const float* scp = sc[le];
#pragma unroll
    for (int k = 0; k < IN_FEATS; ++k)
        acc = fmaf(scp[k], W1s[k * HIDDEN + j], acc);
    float hval = fmaxf(acc, 0.0f) * W2[j];

#pragma unroll
    for (int off = 16; off >= 1; off >>= 1)
        hval += __shfl_down(hval, off, 32);

    if (j == 0) out[e] = hval + b2[0];
}

extern "C" void kernel_launch(void* const* d_in, const int* in_sizes, int n_in,
                              void* d_out, int out_size, void* d_ws, size_t ws_size,
                              hipStream_t stream) {
    // setup_inputs() order: h, src, dst, W1, b1, W2, b2
    const float* h   = (const float*)d_in[0];
    const int*   src = (const int*)d_in[1];
    const int*   dst = (const int*)d_in[2];
    const float* W1  = (const float*)d_in[3];
    const float* b1  = (const float*)d_in[4];
    const float* W2  = (const float*)d_in[5];
    const float* b2  = (const float*)d_in[6];
    float* out = (float*)d_out;

    const int n_nodes = in_sizes[0] / IN_FEATS;   // 40000
    const int n_edges = in_sizes[1];              // 640000

    const size_t p_bytes = (size_t)n_nodes * HIDDEN * sizeof(f16);   // 2.56 MB

    if (ws_size >= p_bytes) {
        f16* p = (f16*)d_ws;
        const int nblocks = (n_nodes + 63) / 64;      // 625
        node_proj_mfma<<<nblocks, 256, 0, stream>>>(h, W1, b1, p, n_nodes);
        const int eblocks = (n_edges + 255) / 256;    // 2500
        edge_mlp_f16<<<eblocks, 256, 0, stream>>>(p, src, dst, W2, b2, out, n_edges);
    } else {
        fused_edge_kernel<<<(n_edges + 7) / 8, 256, 0, stream>>>(
            h, src, dst, W1, b1, W2, b2, out, n_edges);
    }
}